// Round 6
// baseline (883.301 us; speedup 1.0000x reference)
//
#include <hip/hip_runtime.h>
#include <hip/hip_fp16.h>

// Euler neural-ODE scan: B=1024, L=512, S=64, U=32, H=512, dt=0.1.
// 64 blocks x 512 threads (8 waves); block owns 16 batch rows for all steps.
// Round-6 = round-5 structure with the zbuf lo-offset bug fixed (+1024, not
// +2048 -- the +2048 writes corrupted pbuf and left state-lo uninitialized).
//  * GEMM1: pi-permuted W1^T A-frags in regs, z (state hi/lo, K=128) read
//    linear from LDS, two depth-2 accumulator chains summed at the end.
//  * GEMM2 in A-FORM: acc2[ns] = MFMA(hb[a], W2F[a][ns], .) -- C2 is
//    batch-major with IDENTICAL layout in every wave, so cross-wave reduce
//    is element-wise: pbuf writes linear b128, P2 reads linear b64 at
//    ww*1024 + w*128 + 2*lane  -> zero bank conflicts.
//  * P2 ownership: lane (w; l5=lane>>5, r=lane&31) owns
//      s = (w>>1)*16 + (r>>1),  batches b,b+1, b = ((w&1)*2 + l5)*4 + 2*(r&1).
//  * u off the critical path: uacc = b1 + u(t+1)@W1u computed in P2's
//    pbuf-read latency shadow; u loads prefetched 2 steps ahead.
//  * lgkmcnt-only barriers: global traffic never drained at barriers.

typedef _Float16 f16;
typedef __attribute__((ext_vector_type(8))) _Float16 f16x8;
typedef __attribute__((ext_vector_type(2))) float f32x2;
typedef __attribute__((ext_vector_type(4))) float f32x4;

#define MFMA16(a, b, c) __builtin_amdgcn_mfma_f32_16x16x32_f16((a), (b), (c), 0, 0, 0)

#define BAR() do { asm volatile("s_waitcnt lgkmcnt(0)" ::: "memory"); \
                   __builtin_amdgcn_s_barrier();                      \
                   asm volatile("" ::: "memory"); } while (0)

__device__ __forceinline__ float tanh_fast(float x) {
    float t = __builtin_amdgcn_exp2f(x * 2.885390081777927f);  // e^{2x}
    float r = __builtin_amdgcn_rcpf(t + 1.0f);
    return __builtin_fmaf(-2.0f, r, 1.0f);
}

__global__ __launch_bounds__(512, 2)
void euler_kernel(const float* __restrict__ init,
                  const float* __restrict__ uin,
                  const float* __restrict__ W1,
                  const float* __restrict__ b1,
                  const float* __restrict__ W2,
                  const float* __restrict__ b2,
                  float* __restrict__ out) {
    const int L = 512, S = 64, U = 32, H = 512;
    const int tid  = threadIdx.x;
    const int lane = tid & 63;
    const int w    = tid >> 6;      // wave 0..7
    const int g    = lane >> 4;     // k-group 0..3
    const int r16  = lane & 15;
    const int b0   = blockIdx.x * 16;

    // z (state only): chunk(kk,g',r16') = kk*64+g'*16+r16' holds
    // z[k=kk*32+g'*8+j][batch r16'] slot j (hi: chunks 0..127 = f16 0..1023,
    // lo: chunks 128..255 = f16 1024..2047).
    __shared__ f16   zbuf[256 * 8];          // 4 KB
    // GEMM2 partials, slice ww: dw = (s>>4)*256 + (b>>2)*64 + (s&15)*4 + (b&3)
    __shared__ float pbuf[8 * 1024];         // 32 KB

    // ---- W1^T A-fragments, pi-permuted H-columns ----
    f16x8 W1F[4][4];   // state rows (kk 0,1 = hi; 2,3 = lo share W1 rows 0..63)
    f16x8 W1Fu[2][4];  // u rows (hi/lo share W1 rows 64..95)
    #pragma unroll
    for (int kk = 0; kk < 6; ++kk)
      #pragma unroll
      for (int nf = 0; nf < 4; ++nf) {
          const int hcol = w * 64 + 32 * (nf >> 1) + 8 * (r16 >> 2) + 4 * (nf & 1) + (r16 & 3);
          #pragma unroll
          for (int j = 0; j < 8; ++j) {
              int k  = kk * 32 + g * 8 + j;
              int kr = (k < 128) ? (k & 63) : (64 + (k & 31));
              f16 v  = (f16)W1[kr * H + hcol];
              if (kk < 4) W1F[kk][nf][j] = v; else W1Fu[kk - 4][nf][j] = v;
          }
      }
    f32x4 b1v[4];
    #pragma unroll
    for (int nf = 0; nf < 4; ++nf)
        b1v[nf] = *(const f32x4*)&b1[w * 64 + 32 * (nf >> 1) + 4 * (nf & 1) + 8 * g];

    // ---- W2 fragments: lane holds W2[w*64+a*32+g*8+j][ns*16+r16] ----
    f16x8 W2F[2][4];
    #pragma unroll
    for (int a = 0; a < 2; ++a)
      #pragma unroll
      for (int ns = 0; ns < 4; ++ns)
        #pragma unroll
        for (int j = 0; j < 8; ++j) {
            int k = w * 64 + a * 32 + g * 8 + j;
            W2F[a][ns][j] = (f16)W2[k * S + ns * 16 + r16];
        }

    // ---- P2 ownership: s fixed, batches bP, bP+1 ----
    const int l5 = lane >> 5, r = lane & 31;
    const int sP = (w >> 1) * 16 + (r >> 1);
    const int bP = ((w & 1) * 2 + l5) * 4 + 2 * (r & 1);
    const float b2v = b2[sP];
    // z-write slot (hi): chunk = (sP>>5)*64 + ((sP>>3)&3)*16 + bP, slot sP&7
    const int zci = ((sP >> 5) * 64 + ((sP >> 3) & 3) * 16 + bP) * 8 + (sP & 7);

    f32x2 stateF;
    stateF[0] = init[(size_t)(b0 + bP) * S + sP];
    stateF[1] = init[(size_t)(b0 + bP + 1) * S + sP];
    {
        f16 h0 = (f16)stateF[0], h1 = (f16)stateF[1];
        zbuf[zci]            = h0;
        zbuf[zci + 8]        = h1;                         // batch+1 -> chunk+1
        zbuf[zci + 1024]     = (f16)(stateF[0] - (float)h0);
        zbuf[zci + 1024 + 8] = (f16)(stateF[1] - (float)h1);
    }

    // ---- u prologue: uacc = b1 + u(0)@W1u ; prefetch u(1) ----
    const float* uptr = uin + (size_t)(b0 + r16) * L * U + g * 8;
    f32x4 ua0 = *(const f32x4*)uptr;
    f32x4 ua1 = *(const f32x4*)(uptr + 4);
    f32x4 uacc[4];
    #pragma unroll
    for (int nf = 0; nf < 4; ++nf) uacc[nf] = b1v[nf];
    {
        f16x8 uh, ul;
        #pragma unroll
        for (int j = 0; j < 4; ++j) {
            f16 h0 = (f16)ua0[j]; uh[j] = h0;     ul[j] = (f16)(ua0[j] - (float)h0);
            f16 h1 = (f16)ua1[j]; uh[4 + j] = h1; ul[4 + j] = (f16)(ua1[j] - (float)h1);
        }
        #pragma unroll
        for (int nf = 0; nf < 4; ++nf) uacc[nf] = MFMA16(W1Fu[0][nf], uh, uacc[nf]);
        #pragma unroll
        for (int nf = 0; nf < 4; ++nf) uacc[nf] = MFMA16(W1Fu[1][nf], ul, uacc[nf]);
    }
    ua0 = *(const f32x4*)(uptr + U);
    ua1 = *(const f32x4*)(uptr + U + 4);
    BAR();

    #pragma unroll 1
    for (int t = 0; t < L; ++t) {
        // ---- P1: z-read (linear), GEMM1 (2 depth-2 chains), tanh+pack,
        //          GEMM2 A-form, pbuf write (linear) ----
        f16x8 zf[4];
        #pragma unroll
        for (int kk = 0; kk < 4; ++kk)
            zf[kk] = *(const f16x8*)&zbuf[(kk * 64 + lane) * 8];
        f32x4 acc1a[4], acc1b[4];
        #pragma unroll
        for (int nf = 0; nf < 4; ++nf) {
            acc1a[nf] = uacc[nf];
            acc1b[nf] = (f32x4){0.f, 0.f, 0.f, 0.f};
        }
        #pragma unroll
        for (int nf = 0; nf < 4; ++nf) {
            acc1a[nf] = MFMA16(W1F[0][nf], zf[0], acc1a[nf]);
            acc1b[nf] = MFMA16(W1F[2][nf], zf[2], acc1b[nf]);
        }
        #pragma unroll
        for (int nf = 0; nf < 4; ++nf) {
            acc1a[nf] = MFMA16(W1F[1][nf], zf[1], acc1a[nf]);
            acc1b[nf] = MFMA16(W1F[3][nf], zf[3], acc1b[nf]);
        }
        f16x8 hb[2];
        #pragma unroll
        for (int a = 0; a < 2; ++a)
          #pragma unroll
          for (int j8 = 0; j8 < 8; ++j8) {
              int nf = a * 2 + (j8 >> 2), jj = j8 & 3;
              hb[a][j8] = (f16)tanh_fast(acc1a[nf][jj] + acc1b[nf][jj]);
          }
        f32x4 acc2[4];
        #pragma unroll
        for (int ns = 0; ns < 4; ++ns) acc2[ns] = (f32x4){0.f, 0.f, 0.f, 0.f};
        #pragma unroll
        for (int a = 0; a < 2; ++a)
          #pragma unroll
          for (int ns = 0; ns < 4; ++ns)
            acc2[ns] = MFMA16(hb[a], W2F[a][ns], acc2[ns]);   // A-form: C batch-major
        #pragma unroll
        for (int ns = 0; ns < 4; ++ns)
            *(f32x4*)&pbuf[(w * 256 + ns * 64 + lane) * 4] = acc2[ns];
        BAR();

        // ---- P2: linear partial reads; u-work in their latency shadow ----
        f32x2 p[8];
        #pragma unroll
        for (int ww = 0; ww < 8; ++ww)
            p[ww] = *(const f32x2*)&pbuf[ww * 1024 + w * 128 + lane * 2];

        // uacc(t+1) = b1 + u(t+1)@W1u ; prefetch u(t+2)  (shadowed)
        #pragma unroll
        for (int nf = 0; nf < 4; ++nf) uacc[nf] = b1v[nf];
        {
            f16x8 uh, ul;
            #pragma unroll
            for (int j = 0; j < 4; ++j) {
                f16 h0 = (f16)ua0[j]; uh[j] = h0;     ul[j] = (f16)(ua0[j] - (float)h0);
                f16 h1 = (f16)ua1[j]; uh[4 + j] = h1; ul[4 + j] = (f16)(ua1[j] - (float)h1);
            }
            #pragma unroll
            for (int nf = 0; nf < 4; ++nf) uacc[nf] = MFMA16(W1Fu[0][nf], uh, uacc[nf]);
            #pragma unroll
            for (int nf = 0; nf < 4; ++nf) uacc[nf] = MFMA16(W1Fu[1][nf], ul, uacc[nf]);
        }
        {
            int tp = (t + 2 < L) ? (t + 2) : (L - 1);
            ua0 = *(const f32x4*)(uptr + (size_t)tp * U);
            ua1 = *(const f32x4*)(uptr + (size_t)tp * U + 4);
        }

        // tree reduce + state update + z-write + out store
        f32x2 s01 = (f32x2){0.f, 0.f}, s23 = s01, s45 = s01, s67 = s01;
        #pragma unroll
        for (int j = 0; j < 2; ++j) {
            s01[j] = p[0][j] + p[1][j];
            s23[j] = p[2][j] + p[3][j];
            s45[j] = p[4][j] + p[5][j];
            s67[j] = p[6][j] + p[7][j];
        }
        float d0 = ((s01[0] + s23[0]) + (s45[0] + s67[0])) + b2v;
        float d1 = ((s01[1] + s23[1]) + (s45[1] + s67[1])) + b2v;
        float sn0 = __builtin_fmaf(0.1f, d0, stateF[0]);
        float sn1 = __builtin_fmaf(0.1f, d1, stateF[1]);
        stateF[0] = sn0; stateF[1] = sn1;
        f16 h0 = (f16)sn0, h1 = (f16)sn1;
        zbuf[zci]            = h0;
        zbuf[zci + 8]        = h1;
        zbuf[zci + 1024]     = (f16)(sn0 - (float)h0);
        zbuf[zci + 1024 + 8] = (f16)(sn1 - (float)h1);
        out[((size_t)(b0 + bP) * L + t) * S + sP]     = sn0;
        out[((size_t)(b0 + bP + 1) * L + t) * S + sP] = sn1;
        BAR();
    }
}

extern "C" void kernel_launch(void* const* d_in, const int* in_sizes, int n_in,
                              void* d_out, int out_size, void* d_ws, size_t ws_size,
                              hipStream_t stream) {
    const float* init = (const float*)d_in[0];
    const float* uin  = (const float*)d_in[1];
    const float* W1   = (const float*)d_in[2];
    const float* b1   = (const float*)d_in[3];
    const float* W2   = (const float*)d_in[4];
    const float* b2   = (const float*)d_in[5];
    euler_kernel<<<dim3(64), dim3(512), 0, stream>>>(init, uin, W1, b1, W2, b2,
                                                     (float*)d_out);
}

// Round 7
// 882.556 us; speedup vs baseline: 1.0008x; 1.0008x over previous
//
#include <hip/hip_runtime.h>
#include <hip/hip_fp16.h>

// Euler neural-ODE scan: B=1024, L=512, S=64, U=32, H=512, dt=0.1.
// 64 blocks x 512 threads (8 waves); block owns 16 batch rows for all steps.
// Round-7 = round-6 body with __launch_bounds__(512, 1).
//   ROOT CAUSE FOUND: (512,2) capped VGPRs at 128, so the ~170 persistent
//   weight-fragment registers (W1F 64 + W1Fu 32 + W2F 32 + uacc/b1v/ua) were
//   SPILLED TO SCRATCH and re-loaded every step -- the invisible tax in every
//   prior round (VGPR_Count 92-128 << what the design needs). Grid is 64
//   blocks on 256 CUs; 1 block/CU costs nothing.
//  * GEMM1: pi-permuted W1^T A-frags in regs, z (state hi/lo, K=128) read
//    linear from LDS, two depth-2 accumulator chains summed at the end.
//  * GEMM2 in A-FORM: acc2[ns] = MFMA(hb[a], W2F[a][ns], .) -- C2 batch-major,
//    identical layout in every wave; pbuf writes linear b128, P2 reads linear
//    b64 at ww*1024 + w*128 + 2*lane -> zero bank conflicts.
//  * P2 ownership: lane (w; l5=lane>>5, r=lane&31) owns
//      s = (w>>1)*16 + (r>>1),  batches b,b+1, b = ((w&1)*2 + l5)*4 + 2*(r&1).
//  * u off the critical path: uacc = b1 + u(t+1)@W1u computed in P2's
//    pbuf-read latency shadow; u loads prefetched 2 steps ahead.
//  * lgkmcnt-only barriers: global traffic never drained at barriers.

typedef _Float16 f16;
typedef __attribute__((ext_vector_type(8))) _Float16 f16x8;
typedef __attribute__((ext_vector_type(2))) float f32x2;
typedef __attribute__((ext_vector_type(4))) float f32x4;

#define MFMA16(a, b, c) __builtin_amdgcn_mfma_f32_16x16x32_f16((a), (b), (c), 0, 0, 0)

#define BAR() do { asm volatile("s_waitcnt lgkmcnt(0)" ::: "memory"); \
                   __builtin_amdgcn_s_barrier();                      \
                   asm volatile("" ::: "memory"); } while (0)

__device__ __forceinline__ float tanh_fast(float x) {
    float t = __builtin_amdgcn_exp2f(x * 2.885390081777927f);  // e^{2x}
    float r = __builtin_amdgcn_rcpf(t + 1.0f);
    return __builtin_fmaf(-2.0f, r, 1.0f);
}

__global__ __launch_bounds__(512, 1)
void euler_kernel(const float* __restrict__ init,
                  const float* __restrict__ uin,
                  const float* __restrict__ W1,
                  const float* __restrict__ b1,
                  const float* __restrict__ W2,
                  const float* __restrict__ b2,
                  float* __restrict__ out) {
    const int L = 512, S = 64, U = 32, H = 512;
    const int tid  = threadIdx.x;
    const int lane = tid & 63;
    const int w    = tid >> 6;      // wave 0..7
    const int g    = lane >> 4;     // k-group 0..3
    const int r16  = lane & 15;
    const int b0   = blockIdx.x * 16;

    // z (state only): chunk(kk,g',r16') = kk*64+g'*16+r16' holds
    // z[k=kk*32+g'*8+j][batch r16'] slot j (hi: chunks 0..127 = f16 0..1023,
    // lo: chunks 128..255 = f16 1024..2047).
    __shared__ f16   zbuf[256 * 8];          // 4 KB
    // GEMM2 partials, slice ww: dw = (s>>4)*256 + (b>>2)*64 + (s&15)*4 + (b&3)
    __shared__ float pbuf[8 * 1024];         // 32 KB

    // ---- W1^T A-fragments, pi-permuted H-columns ----
    f16x8 W1F[4][4];   // state rows (kk 0,1 = hi; 2,3 = lo share W1 rows 0..63)
    f16x8 W1Fu[2][4];  // u rows (hi/lo share W1 rows 64..95)
    #pragma unroll
    for (int kk = 0; kk < 6; ++kk)
      #pragma unroll
      for (int nf = 0; nf < 4; ++nf) {
          const int hcol = w * 64 + 32 * (nf >> 1) + 8 * (r16 >> 2) + 4 * (nf & 1) + (r16 & 3);
          #pragma unroll
          for (int j = 0; j < 8; ++j) {
              int k  = kk * 32 + g * 8 + j;
              int kr = (k < 128) ? (k & 63) : (64 + (k & 31));
              f16 v  = (f16)W1[kr * H + hcol];
              if (kk < 4) W1F[kk][nf][j] = v; else W1Fu[kk - 4][nf][j] = v;
          }
      }
    f32x4 b1v[4];
    #pragma unroll
    for (int nf = 0; nf < 4; ++nf)
        b1v[nf] = *(const f32x4*)&b1[w * 64 + 32 * (nf >> 1) + 4 * (nf & 1) + 8 * g];

    // ---- W2 fragments: lane holds W2[w*64+a*32+g*8+j][ns*16+r16] ----
    f16x8 W2F[2][4];
    #pragma unroll
    for (int a = 0; a < 2; ++a)
      #pragma unroll
      for (int ns = 0; ns < 4; ++ns)
        #pragma unroll
        for (int j = 0; j < 8; ++j) {
            int k = w * 64 + a * 32 + g * 8 + j;
            W2F[a][ns][j] = (f16)W2[k * S + ns * 16 + r16];
        }

    // ---- P2 ownership: s fixed, batches bP, bP+1 ----
    const int l5 = lane >> 5, r = lane & 31;
    const int sP = (w >> 1) * 16 + (r >> 1);
    const int bP = ((w & 1) * 2 + l5) * 4 + 2 * (r & 1);
    const float b2v = b2[sP];
    // z-write slot (hi): chunk = (sP>>5)*64 + ((sP>>3)&3)*16 + bP, slot sP&7
    const int zci = ((sP >> 5) * 64 + ((sP >> 3) & 3) * 16 + bP) * 8 + (sP & 7);

    f32x2 stateF;
    stateF[0] = init[(size_t)(b0 + bP) * S + sP];
    stateF[1] = init[(size_t)(b0 + bP + 1) * S + sP];
    {
        f16 h0 = (f16)stateF[0], h1 = (f16)stateF[1];
        zbuf[zci]            = h0;
        zbuf[zci + 8]        = h1;                         // batch+1 -> chunk+1
        zbuf[zci + 1024]     = (f16)(stateF[0] - (float)h0);
        zbuf[zci + 1024 + 8] = (f16)(stateF[1] - (float)h1);
    }

    // ---- u prologue: uacc = b1 + u(0)@W1u ; prefetch u(1) ----
    const float* uptr = uin + (size_t)(b0 + r16) * L * U + g * 8;
    f32x4 ua0 = *(const f32x4*)uptr;
    f32x4 ua1 = *(const f32x4*)(uptr + 4);
    f32x4 uacc[4];
    #pragma unroll
    for (int nf = 0; nf < 4; ++nf) uacc[nf] = b1v[nf];
    {
        f16x8 uh, ul;
        #pragma unroll
        for (int j = 0; j < 4; ++j) {
            f16 h0 = (f16)ua0[j]; uh[j] = h0;     ul[j] = (f16)(ua0[j] - (float)h0);
            f16 h1 = (f16)ua1[j]; uh[4 + j] = h1; ul[4 + j] = (f16)(ua1[j] - (float)h1);
        }
        #pragma unroll
        for (int nf = 0; nf < 4; ++nf) uacc[nf] = MFMA16(W1Fu[0][nf], uh, uacc[nf]);
        #pragma unroll
        for (int nf = 0; nf < 4; ++nf) uacc[nf] = MFMA16(W1Fu[1][nf], ul, uacc[nf]);
    }
    ua0 = *(const f32x4*)(uptr + U);
    ua1 = *(const f32x4*)(uptr + U + 4);
    BAR();

    #pragma unroll 1
    for (int t = 0; t < L; ++t) {
        // ---- P1: z-read (linear), GEMM1 (2 depth-2 chains), tanh+pack,
        //          GEMM2 A-form, pbuf write (linear) ----
        f16x8 zf[4];
        #pragma unroll
        for (int kk = 0; kk < 4; ++kk)
            zf[kk] = *(const f16x8*)&zbuf[(kk * 64 + lane) * 8];
        f32x4 acc1a[4], acc1b[4];
        #pragma unroll
        for (int nf = 0; nf < 4; ++nf) {
            acc1a[nf] = uacc[nf];
            acc1b[nf] = (f32x4){0.f, 0.f, 0.f, 0.f};
        }
        #pragma unroll
        for (int nf = 0; nf < 4; ++nf) {
            acc1a[nf] = MFMA16(W1F[0][nf], zf[0], acc1a[nf]);
            acc1b[nf] = MFMA16(W1F[2][nf], zf[2], acc1b[nf]);
        }
        #pragma unroll
        for (int nf = 0; nf < 4; ++nf) {
            acc1a[nf] = MFMA16(W1F[1][nf], zf[1], acc1a[nf]);
            acc1b[nf] = MFMA16(W1F[3][nf], zf[3], acc1b[nf]);
        }
        f16x8 hb[2];
        #pragma unroll
        for (int a = 0; a < 2; ++a)
          #pragma unroll
          for (int j8 = 0; j8 < 8; ++j8) {
              int nf = a * 2 + (j8 >> 2), jj = j8 & 3;
              hb[a][j8] = (f16)tanh_fast(acc1a[nf][jj] + acc1b[nf][jj]);
          }
        f32x4 acc2[4];
        #pragma unroll
        for (int ns = 0; ns < 4; ++ns) acc2[ns] = (f32x4){0.f, 0.f, 0.f, 0.f};
        #pragma unroll
        for (int a = 0; a < 2; ++a)
          #pragma unroll
          for (int ns = 0; ns < 4; ++ns)
            acc2[ns] = MFMA16(hb[a], W2F[a][ns], acc2[ns]);   // A-form: C batch-major
        #pragma unroll
        for (int ns = 0; ns < 4; ++ns)
            *(f32x4*)&pbuf[(w * 256 + ns * 64 + lane) * 4] = acc2[ns];
        BAR();

        // ---- P2: linear partial reads; u-work in their latency shadow ----
        f32x2 p[8];
        #pragma unroll
        for (int ww = 0; ww < 8; ++ww)
            p[ww] = *(const f32x2*)&pbuf[ww * 1024 + w * 128 + lane * 2];

        // uacc(t+1) = b1 + u(t+1)@W1u ; prefetch u(t+2)  (shadowed)
        #pragma unroll
        for (int nf = 0; nf < 4; ++nf) uacc[nf] = b1v[nf];
        {
            f16x8 uh, ul;
            #pragma unroll
            for (int j = 0; j < 4; ++j) {
                f16 h0 = (f16)ua0[j]; uh[j] = h0;     ul[j] = (f16)(ua0[j] - (float)h0);
                f16 h1 = (f16)ua1[j]; uh[4 + j] = h1; ul[4 + j] = (f16)(ua1[j] - (float)h1);
            }
            #pragma unroll
            for (int nf = 0; nf < 4; ++nf) uacc[nf] = MFMA16(W1Fu[0][nf], uh, uacc[nf]);
            #pragma unroll
            for (int nf = 0; nf < 4; ++nf) uacc[nf] = MFMA16(W1Fu[1][nf], ul, uacc[nf]);
        }
        {
            int tp = (t + 2 < L) ? (t + 2) : (L - 1);
            ua0 = *(const f32x4*)(uptr + (size_t)tp * U);
            ua1 = *(const f32x4*)(uptr + (size_t)tp * U + 4);
        }

        // tree reduce + state update + z-write + out store
        f32x2 s01 = (f32x2){0.f, 0.f}, s23 = s01, s45 = s01, s67 = s01;
        #pragma unroll
        for (int j = 0; j < 2; ++j) {
            s01[j] = p[0][j] + p[1][j];
            s23[j] = p[2][j] + p[3][j];
            s45[j] = p[4][j] + p[5][j];
            s67[j] = p[6][j] + p[7][j];
        }
        float d0 = ((s01[0] + s23[0]) + (s45[0] + s67[0])) + b2v;
        float d1 = ((s01[1] + s23[1]) + (s45[1] + s67[1])) + b2v;
        float sn0 = __builtin_fmaf(0.1f, d0, stateF[0]);
        float sn1 = __builtin_fmaf(0.1f, d1, stateF[1]);
        stateF[0] = sn0; stateF[1] = sn1;
        f16 h0 = (f16)sn0, h1 = (f16)sn1;
        zbuf[zci]            = h0;
        zbuf[zci + 8]        = h1;
        zbuf[zci + 1024]     = (f16)(sn0 - (float)h0);
        zbuf[zci + 1024 + 8] = (f16)(sn1 - (float)h1);
        out[((size_t)(b0 + bP) * L + t) * S + sP]     = sn0;
        out[((size_t)(b0 + bP + 1) * L + t) * S + sP] = sn1;
        BAR();
    }
}

extern "C" void kernel_launch(void* const* d_in, const int* in_sizes, int n_in,
                              void* d_out, int out_size, void* d_ws, size_t ws_size,
                              hipStream_t stream) {
    const float* init = (const float*)d_in[0];
    const float* uin  = (const float*)d_in[1];
    const float* W1   = (const float*)d_in[2];
    const float* b1   = (const float*)d_in[3];
    const float* W2   = (const float*)d_in[4];
    const float* b2   = (const float*)d_in[5];
    euler_kernel<<<dim3(64), dim3(512), 0, stream>>>(init, uin, W1, b1, W2, b2,
                                                     (float*)d_out);
}

// Round 9
// 663.246 us; speedup vs baseline: 1.3318x; 1.3307x over previous
//
#include <hip/hip_runtime.h>
#include <hip/hip_fp16.h>

// Euler neural-ODE scan: B=1024, L=512, S=64, U=32, H=512, dt=0.1.
// 64 blocks x 512 threads (8 waves); block owns 16 batch rows for all steps.
// Round-9 = round-8 with the pkrtz return-type compile fix (bit_cast from
// the builtin's __fp16 vector to our _Float16 vector; identical layout).
//  * u-block (split-pack + 8 MFMAs + t+2 prefetch) in P1's tail, AFTER the
//    pbuf write and BEFORE BAR-A (fills barrier-arrival skew) -- round-4
//    placement; round 6/7 had it on P2's serial path (+480 cyc/step).
//  * GEMM1: pi-permuted W1^T A-frags in regs, z (state hi/lo, K=128) read
//    linear from LDS, two depth-2 accumulator chains summed at the end.
//  * GEMM2 A-form: C2 batch-major, identical layout in every wave; pbuf
//    writes linear b128, P2 reads linear b64 -> zero bank conflicts.
//  * P2 ownership: lane (w; l5=lane>>5, r=lane&31) owns
//      s = (w>>1)*16 + (r>>1), batches b,b+1, b = ((w&1)*2+l5)*4 + 2*(r&1).
//  * v_cvt_pkrtz for hi/lo SPLIT sites only (pair-sum exact to ~2^-21;
//    tanh->f16 stays RTN to avoid biasing h).
//  * lgkmcnt-only barriers: global traffic never drained at barriers.

typedef _Float16 f16;
typedef __attribute__((ext_vector_type(2))) _Float16 f16x2;
typedef __attribute__((ext_vector_type(8))) _Float16 f16x8;
typedef __attribute__((ext_vector_type(2))) float f32x2;
typedef __attribute__((ext_vector_type(4))) float f32x4;

#define MFMA16(a, b, c) __builtin_amdgcn_mfma_f32_16x16x32_f16((a), (b), (c), 0, 0, 0)

#define BAR() do { asm volatile("s_waitcnt lgkmcnt(0)" ::: "memory"); \
                   __builtin_amdgcn_s_barrier();                      \
                   asm volatile("" ::: "memory"); } while (0)

__device__ __forceinline__ f16x2 pkrtz(float a, float b) {
    return __builtin_bit_cast(f16x2, __builtin_amdgcn_cvt_pkrtz(a, b));
}

__device__ __forceinline__ float tanh_fast(float x) {
    float t = __builtin_amdgcn_exp2f(x * 2.885390081777927f);  // e^{2x}
    float r = __builtin_amdgcn_rcpf(t + 1.0f);
    return __builtin_fmaf(-2.0f, r, 1.0f);
}

__global__ __launch_bounds__(512, 1)
void euler_kernel(const float* __restrict__ init,
                  const float* __restrict__ uin,
                  const float* __restrict__ W1,
                  const float* __restrict__ b1,
                  const float* __restrict__ W2,
                  const float* __restrict__ b2,
                  float* __restrict__ out) {
    const int L = 512, S = 64, U = 32, H = 512;
    const int tid  = threadIdx.x;
    const int lane = tid & 63;
    const int w    = tid >> 6;      // wave 0..7
    const int g    = lane >> 4;     // k-group 0..3
    const int r16  = lane & 15;
    const int b0   = blockIdx.x * 16;

    // z (state only): chunk(kk,g',r16') = kk*64+g'*16+r16' holds
    // z[k=kk*32+g'*8+j][batch r16'] slot j (hi: f16 0..1023, lo: 1024..2047).
    __shared__ f16   zbuf[256 * 8];          // 4 KB
    // GEMM2 partials, slice ww: dw = (s>>4)*256 + (b>>2)*64 + (s&15)*4 + (b&3)
    __shared__ float pbuf[8 * 1024];         // 32 KB

    // ---- W1^T A-fragments, pi-permuted H-columns ----
    f16x8 W1F[4][4];   // state rows (kk 0,1 = hi; 2,3 = lo share W1 rows 0..63)
    f16x8 W1Fu[2][4];  // u rows (hi/lo share W1 rows 64..95)
    #pragma unroll
    for (int kk = 0; kk < 6; ++kk)
      #pragma unroll
      for (int nf = 0; nf < 4; ++nf) {
          const int hcol = w * 64 + 32 * (nf >> 1) + 8 * (r16 >> 2) + 4 * (nf & 1) + (r16 & 3);
          #pragma unroll
          for (int j = 0; j < 8; ++j) {
              int k  = kk * 32 + g * 8 + j;
              int kr = (k < 128) ? (k & 63) : (64 + (k & 31));
              f16 v  = (f16)W1[kr * H + hcol];
              if (kk < 4) W1F[kk][nf][j] = v; else W1Fu[kk - 4][nf][j] = v;
          }
      }
    f32x4 b1v[4];
    #pragma unroll
    for (int nf = 0; nf < 4; ++nf)
        b1v[nf] = *(const f32x4*)&b1[w * 64 + 32 * (nf >> 1) + 4 * (nf & 1) + 8 * g];

    // ---- W2 fragments: lane holds W2[w*64+a*32+g*8+j][ns*16+r16] ----
    f16x8 W2F[2][4];
    #pragma unroll
    for (int a = 0; a < 2; ++a)
      #pragma unroll
      for (int ns = 0; ns < 4; ++ns)
        #pragma unroll
        for (int j = 0; j < 8; ++j) {
            int k = w * 64 + a * 32 + g * 8 + j;
            W2F[a][ns][j] = (f16)W2[k * S + ns * 16 + r16];
        }

    // ---- P2 ownership: s fixed, batches bP, bP+1 ----
    const int l5 = lane >> 5, r = lane & 31;
    const int sP = (w >> 1) * 16 + (r >> 1);
    const int bP = ((w & 1) * 2 + l5) * 4 + 2 * (r & 1);
    const float b2v = b2[sP];
    // z-write slot (hi): chunk = (sP>>5)*64 + ((sP>>3)&3)*16 + bP, slot sP&7
    const int zci = ((sP >> 5) * 64 + ((sP >> 3) & 3) * 16 + bP) * 8 + (sP & 7);

    f32x2 stateF;
    stateF[0] = init[(size_t)(b0 + bP) * S + sP];
    stateF[1] = init[(size_t)(b0 + bP + 1) * S + sP];
    {
        f16x2 sh = pkrtz(stateF[0], stateF[1]);
        f16x2 sl = pkrtz(stateF[0] - (float)sh[0], stateF[1] - (float)sh[1]);
        zbuf[zci]            = sh[0];
        zbuf[zci + 8]        = sh[1];                      // batch+1 -> chunk+1
        zbuf[zci + 1024]     = sl[0];
        zbuf[zci + 1024 + 8] = sl[1];
    }

    // ---- u prologue: uacc = b1 + u(0)@W1u ; prefetch u(1) ----
    const float* uptr = uin + (size_t)(b0 + r16) * L * U + g * 8;
    f32x4 ua0 = *(const f32x4*)uptr;
    f32x4 ua1 = *(const f32x4*)(uptr + 4);
    f32x4 uacc[4];
    #pragma unroll
    for (int nf = 0; nf < 4; ++nf) uacc[nf] = b1v[nf];
    {
        f16x2 a01 = pkrtz(ua0[0], ua0[1]), a23 = pkrtz(ua0[2], ua0[3]);
        f16x2 c01 = pkrtz(ua1[0], ua1[1]), c23 = pkrtz(ua1[2], ua1[3]);
        f16x2 la  = pkrtz(ua0[0] - (float)a01[0], ua0[1] - (float)a01[1]);
        f16x2 lb  = pkrtz(ua0[2] - (float)a23[0], ua0[3] - (float)a23[1]);
        f16x2 lc  = pkrtz(ua1[0] - (float)c01[0], ua1[1] - (float)c01[1]);
        f16x2 ld  = pkrtz(ua1[2] - (float)c23[0], ua1[3] - (float)c23[1]);
        f16x8 uh, ul;
        uh[0]=a01[0]; uh[1]=a01[1]; uh[2]=a23[0]; uh[3]=a23[1];
        uh[4]=c01[0]; uh[5]=c01[1]; uh[6]=c23[0]; uh[7]=c23[1];
        ul[0]=la[0];  ul[1]=la[1];  ul[2]=lb[0];  ul[3]=lb[1];
        ul[4]=lc[0];  ul[5]=lc[1];  ul[6]=ld[0];  ul[7]=ld[1];
        #pragma unroll
        for (int nf = 0; nf < 4; ++nf) uacc[nf] = MFMA16(W1Fu[0][nf], uh, uacc[nf]);
        #pragma unroll
        for (int nf = 0; nf < 4; ++nf) uacc[nf] = MFMA16(W1Fu[1][nf], ul, uacc[nf]);
    }
    ua0 = *(const f32x4*)(uptr + U);
    ua1 = *(const f32x4*)(uptr + U + 4);
    BAR();

    #pragma unroll 1
    for (int t = 0; t < L; ++t) {
        // ---- P1: z-read (linear), GEMM1 (2 depth-2 chains), tanh+pack,
        //          GEMM2 A-form, pbuf write (linear) ----
        f16x8 zf[4];
        #pragma unroll
        for (int kk = 0; kk < 4; ++kk)
            zf[kk] = *(const f16x8*)&zbuf[(kk * 64 + lane) * 8];
        f32x4 acc1a[4], acc1b[4];
        #pragma unroll
        for (int nf = 0; nf < 4; ++nf) {
            acc1a[nf] = uacc[nf];
            acc1b[nf] = (f32x4){0.f, 0.f, 0.f, 0.f};
        }
        #pragma unroll
        for (int nf = 0; nf < 4; ++nf) {
            acc1a[nf] = MFMA16(W1F[0][nf], zf[0], acc1a[nf]);
            acc1b[nf] = MFMA16(W1F[2][nf], zf[2], acc1b[nf]);
        }
        #pragma unroll
        for (int nf = 0; nf < 4; ++nf) {
            acc1a[nf] = MFMA16(W1F[1][nf], zf[1], acc1a[nf]);
            acc1b[nf] = MFMA16(W1F[3][nf], zf[3], acc1b[nf]);
        }
        f16x8 hb[2];
        #pragma unroll
        for (int a = 0; a < 2; ++a)
          #pragma unroll
          for (int j8 = 0; j8 < 8; ++j8) {
              int nf = a * 2 + (j8 >> 2), jj = j8 & 3;
              hb[a][j8] = (f16)tanh_fast(acc1a[nf][jj] + acc1b[nf][jj]);  // RTN
          }
        f32x4 acc2[4];
        #pragma unroll
        for (int ns = 0; ns < 4; ++ns) acc2[ns] = (f32x4){0.f, 0.f, 0.f, 0.f};
        #pragma unroll
        for (int a = 0; a < 2; ++a)
          #pragma unroll
          for (int ns = 0; ns < 4; ++ns)
            acc2[ns] = MFMA16(hb[a], W2F[a][ns], acc2[ns]);   // A-form: C batch-major
        #pragma unroll
        for (int ns = 0; ns < 4; ++ns)
            *(f32x4*)&pbuf[(w * 256 + ns * 64 + lane) * 4] = acc2[ns];

        // ---- u-block in P1 tail (fills barrier skew, round-4 placement):
        //      uacc(t+1) = b1 + u(t+1)@W1u ; prefetch u(t+2) ----
        #pragma unroll
        for (int nf = 0; nf < 4; ++nf) uacc[nf] = b1v[nf];
        {
            f16x2 a01 = pkrtz(ua0[0], ua0[1]), a23 = pkrtz(ua0[2], ua0[3]);
            f16x2 c01 = pkrtz(ua1[0], ua1[1]), c23 = pkrtz(ua1[2], ua1[3]);
            f16x2 la  = pkrtz(ua0[0] - (float)a01[0], ua0[1] - (float)a01[1]);
            f16x2 lb  = pkrtz(ua0[2] - (float)a23[0], ua0[3] - (float)a23[1]);
            f16x2 lc  = pkrtz(ua1[0] - (float)c01[0], ua1[1] - (float)c01[1]);
            f16x2 ld  = pkrtz(ua1[2] - (float)c23[0], ua1[3] - (float)c23[1]);
            f16x8 uh, ul;
            uh[0]=a01[0]; uh[1]=a01[1]; uh[2]=a23[0]; uh[3]=a23[1];
            uh[4]=c01[0]; uh[5]=c01[1]; uh[6]=c23[0]; uh[7]=c23[1];
            ul[0]=la[0];  ul[1]=la[1];  ul[2]=lb[0];  ul[3]=lb[1];
            ul[4]=lc[0];  ul[5]=lc[1];  ul[6]=ld[0];  ul[7]=ld[1];
            #pragma unroll
            for (int nf = 0; nf < 4; ++nf) uacc[nf] = MFMA16(W1Fu[0][nf], uh, uacc[nf]);
            #pragma unroll
            for (int nf = 0; nf < 4; ++nf) uacc[nf] = MFMA16(W1Fu[1][nf], ul, uacc[nf]);
        }
        {
            int tp = (t + 2 < L) ? (t + 2) : (L - 1);
            ua0 = *(const f32x4*)(uptr + (size_t)tp * U);
            ua1 = *(const f32x4*)(uptr + (size_t)tp * U + 4);
        }
        BAR();

        // ---- P2: linear partial reads, tree reduce, state update,
        //          out store, z-write ----
        f32x2 p[8];
        #pragma unroll
        for (int ww = 0; ww < 8; ++ww)
            p[ww] = *(const f32x2*)&pbuf[ww * 1024 + w * 128 + lane * 2];

        f32x2 s01 = (f32x2){0.f, 0.f}, s23 = s01, s45 = s01, s67 = s01;
        #pragma unroll
        for (int j = 0; j < 2; ++j) {
            s01[j] = p[0][j] + p[1][j];
            s23[j] = p[2][j] + p[3][j];
            s45[j] = p[4][j] + p[5][j];
            s67[j] = p[6][j] + p[7][j];
        }
        float d0 = ((s01[0] + s23[0]) + (s45[0] + s67[0])) + b2v;
        float d1 = ((s01[1] + s23[1]) + (s45[1] + s67[1])) + b2v;
        float sn0 = __builtin_fmaf(0.1f, d0, stateF[0]);
        float sn1 = __builtin_fmaf(0.1f, d1, stateF[1]);
        stateF[0] = sn0; stateF[1] = sn1;
        f16x2 sh = pkrtz(sn0, sn1);
        f16x2 sl = pkrtz(sn0 - (float)sh[0], sn1 - (float)sh[1]);
        zbuf[zci]            = sh[0];
        zbuf[zci + 8]        = sh[1];
        zbuf[zci + 1024]     = sl[0];
        zbuf[zci + 1024 + 8] = sl[1];
        out[((size_t)(b0 + bP) * L + t) * S + sP]     = sn0;
        out[((size_t)(b0 + bP + 1) * L + t) * S + sP] = sn1;
        BAR();
    }
}

extern "C" void kernel_launch(void* const* d_in, const int* in_sizes, int n_in,
                              void* d_out, int out_size, void* d_ws, size_t ws_size,
                              hipStream_t stream) {
    const float* init = (const float*)d_in[0];
    const float* uin  = (const float*)d_in[1];
    const float* W1   = (const float*)d_in[2];
    const float* b1   = (const float*)d_in[3];
    const float* W2   = (const float*)d_in[4];
    const float* b2   = (const float*)d_in[5];
    euler_kernel<<<dim3(64), dim3(512), 0, stream>>>(init, uin, W1, b1, W2, b2,
                                                     (float*)d_out);
}

// Round 10
// 637.840 us; speedup vs baseline: 1.3848x; 1.0398x over previous
//
#include <hip/hip_runtime.h>
#include <hip/hip_fp16.h>

// Euler neural-ODE scan: B=1024, L=512, S=64, U=32, H=512, dt=0.1.
// 64 blocks x 512 threads (8 waves); block owns 16 batch rows for all steps.
// Round-10 = round-9 with two isolated consolidations:
//  (1) plain __syncthreads() barriers (A/B vs the inline-asm lgkm-only BAR
//      -- the only unisolated delta from round 3's 600us besides P2 width;
//      the opaque asm may have blocked compiler scheduling across barriers).
//  (2) GEMM1 as a SINGLE depth-4 chain accumulating IN-PLACE into uacc:
//      deletes 16 acc copies + 16 zero-inits + 16 adds per step. We are
//      VALU-issue-bound (active-CU VALUBusy ~58%), so fewer instructions
//      beats shorter dependency chains.
//  * u-block (split-pack + 8 MFMAs + t+2 prefetch) in P1's tail.
//  * GEMM1: pi-permuted W1^T A-frags in regs, z (state hi/lo, K=128) read
//    linear from LDS.
//  * GEMM2 A-form: C2 batch-major, identical layout in every wave; pbuf
//    writes linear b128, P2 reads linear b64 -> zero bank conflicts.
//  * P2 ownership: lane (w; l5=lane>>5, r=lane&31) owns
//      s = (w>>1)*16 + (r>>1), batches b,b+1, b = ((w&1)*2+l5)*4 + 2*(r&1).
//  * v_cvt_pkrtz for hi/lo SPLIT sites only (pair-sum exact to ~2^-21;
//    tanh->f16 stays RTN).

typedef _Float16 f16;
typedef __attribute__((ext_vector_type(2))) _Float16 f16x2;
typedef __attribute__((ext_vector_type(8))) _Float16 f16x8;
typedef __attribute__((ext_vector_type(2))) float f32x2;
typedef __attribute__((ext_vector_type(4))) float f32x4;

#define MFMA16(a, b, c) __builtin_amdgcn_mfma_f32_16x16x32_f16((a), (b), (c), 0, 0, 0)

__device__ __forceinline__ f16x2 pkrtz(float a, float b) {
    return __builtin_bit_cast(f16x2, __builtin_amdgcn_cvt_pkrtz(a, b));
}

__device__ __forceinline__ float tanh_fast(float x) {
    float t = __builtin_amdgcn_exp2f(x * 2.885390081777927f);  // e^{2x}
    float r = __builtin_amdgcn_rcpf(t + 1.0f);
    return __builtin_fmaf(-2.0f, r, 1.0f);
}

__global__ __launch_bounds__(512, 1)
void euler_kernel(const float* __restrict__ init,
                  const float* __restrict__ uin,
                  const float* __restrict__ W1,
                  const float* __restrict__ b1,
                  const float* __restrict__ W2,
                  const float* __restrict__ b2,
                  float* __restrict__ out) {
    const int L = 512, S = 64, U = 32, H = 512;
    const int tid  = threadIdx.x;
    const int lane = tid & 63;
    const int w    = tid >> 6;      // wave 0..7
    const int g    = lane >> 4;     // k-group 0..3
    const int r16  = lane & 15;
    const int b0   = blockIdx.x * 16;

    // z (state only): chunk(kk,g',r16') = kk*64+g'*16+r16' holds
    // z[k=kk*32+g'*8+j][batch r16'] slot j (hi: f16 0..1023, lo: 1024..2047).
    __shared__ f16   zbuf[256 * 8];          // 4 KB
    // GEMM2 partials, slice ww: dw = (s>>4)*256 + (b>>2)*64 + (s&15)*4 + (b&3)
    __shared__ float pbuf[8 * 1024];         // 32 KB

    // ---- W1^T A-fragments, pi-permuted H-columns ----
    f16x8 W1F[4][4];   // state rows (kk 0,1 = hi; 2,3 = lo share W1 rows 0..63)
    f16x8 W1Fu[2][4];  // u rows (hi/lo share W1 rows 64..95)
    #pragma unroll
    for (int kk = 0; kk < 6; ++kk)
      #pragma unroll
      for (int nf = 0; nf < 4; ++nf) {
          const int hcol = w * 64 + 32 * (nf >> 1) + 8 * (r16 >> 2) + 4 * (nf & 1) + (r16 & 3);
          #pragma unroll
          for (int j = 0; j < 8; ++j) {
              int k  = kk * 32 + g * 8 + j;
              int kr = (k < 128) ? (k & 63) : (64 + (k & 31));
              f16 v  = (f16)W1[kr * H + hcol];
              if (kk < 4) W1F[kk][nf][j] = v; else W1Fu[kk - 4][nf][j] = v;
          }
      }
    f32x4 b1v[4];
    #pragma unroll
    for (int nf = 0; nf < 4; ++nf)
        b1v[nf] = *(const f32x4*)&b1[w * 64 + 32 * (nf >> 1) + 4 * (nf & 1) + 8 * g];

    // ---- W2 fragments: lane holds W2[w*64+a*32+g*8+j][ns*16+r16] ----
    f16x8 W2F[2][4];
    #pragma unroll
    for (int a = 0; a < 2; ++a)
      #pragma unroll
      for (int ns = 0; ns < 4; ++ns)
        #pragma unroll
        for (int j = 0; j < 8; ++j) {
            int k = w * 64 + a * 32 + g * 8 + j;
            W2F[a][ns][j] = (f16)W2[k * S + ns * 16 + r16];
        }

    // ---- P2 ownership: s fixed, batches bP, bP+1 ----
    const int l5 = lane >> 5, r = lane & 31;
    const int sP = (w >> 1) * 16 + (r >> 1);
    const int bP = ((w & 1) * 2 + l5) * 4 + 2 * (r & 1);
    const float b2v = b2[sP];
    // z-write slot (hi): chunk = (sP>>5)*64 + ((sP>>3)&3)*16 + bP, slot sP&7
    const int zci = ((sP >> 5) * 64 + ((sP >> 3) & 3) * 16 + bP) * 8 + (sP & 7);

    f32x2 stateF;
    stateF[0] = init[(size_t)(b0 + bP) * S + sP];
    stateF[1] = init[(size_t)(b0 + bP + 1) * S + sP];
    {
        f16x2 sh = pkrtz(stateF[0], stateF[1]);
        f16x2 sl = pkrtz(stateF[0] - (float)sh[0], stateF[1] - (float)sh[1]);
        zbuf[zci]            = sh[0];
        zbuf[zci + 8]        = sh[1];                      // batch+1 -> chunk+1
        zbuf[zci + 1024]     = sl[0];
        zbuf[zci + 1024 + 8] = sl[1];
    }

    // ---- u prologue: uacc = b1 + u(0)@W1u ; prefetch u(1) ----
    const float* uptr = uin + (size_t)(b0 + r16) * L * U + g * 8;
    f32x4 ua0 = *(const f32x4*)uptr;
    f32x4 ua1 = *(const f32x4*)(uptr + 4);
    f32x4 uacc[4];
    #pragma unroll
    for (int nf = 0; nf < 4; ++nf) uacc[nf] = b1v[nf];
    {
        f16x2 a01 = pkrtz(ua0[0], ua0[1]), a23 = pkrtz(ua0[2], ua0[3]);
        f16x2 c01 = pkrtz(ua1[0], ua1[1]), c23 = pkrtz(ua1[2], ua1[3]);
        f16x2 la  = pkrtz(ua0[0] - (float)a01[0], ua0[1] - (float)a01[1]);
        f16x2 lb  = pkrtz(ua0[2] - (float)a23[0], ua0[3] - (float)a23[1]);
        f16x2 lc  = pkrtz(ua1[0] - (float)c01[0], ua1[1] - (float)c01[1]);
        f16x2 ld  = pkrtz(ua1[2] - (float)c23[0], ua1[3] - (float)c23[1]);
        f16x8 uh, ul;
        uh[0]=a01[0]; uh[1]=a01[1]; uh[2]=a23[0]; uh[3]=a23[1];
        uh[4]=c01[0]; uh[5]=c01[1]; uh[6]=c23[0]; uh[7]=c23[1];
        ul[0]=la[0];  ul[1]=la[1];  ul[2]=lb[0];  ul[3]=lb[1];
        ul[4]=lc[0];  ul[5]=lc[1];  ul[6]=ld[0];  ul[7]=ld[1];
        #pragma unroll
        for (int nf = 0; nf < 4; ++nf) uacc[nf] = MFMA16(W1Fu[0][nf], uh, uacc[nf]);
        #pragma unroll
        for (int nf = 0; nf < 4; ++nf) uacc[nf] = MFMA16(W1Fu[1][nf], ul, uacc[nf]);
    }
    ua0 = *(const f32x4*)(uptr + U);
    ua1 = *(const f32x4*)(uptr + U + 4);
    __syncthreads();

    #pragma unroll 1
    for (int t = 0; t < L; ++t) {
        // ---- P1: z-read (linear), GEMM1 (single depth-4 chain, in-place
        //          into uacc), tanh+pack, GEMM2 A-form, pbuf write ----
        f16x8 zf[4];
        #pragma unroll
        for (int kk = 0; kk < 4; ++kk)
            zf[kk] = *(const f16x8*)&zbuf[(kk * 64 + lane) * 8];
        #pragma unroll
        for (int kk = 0; kk < 4; ++kk)
          #pragma unroll
          for (int nf = 0; nf < 4; ++nf)
            uacc[nf] = MFMA16(W1F[kk][nf], zf[kk], uacc[nf]);
        f16x8 hb[2];
        #pragma unroll
        for (int a = 0; a < 2; ++a)
          #pragma unroll
          for (int j8 = 0; j8 < 8; ++j8) {
              int nf = a * 2 + (j8 >> 2), jj = j8 & 3;
              hb[a][j8] = (f16)tanh_fast(uacc[nf][jj]);  // RTN
          }
        f32x4 acc2[4];
        #pragma unroll
        for (int ns = 0; ns < 4; ++ns) acc2[ns] = (f32x4){0.f, 0.f, 0.f, 0.f};
        #pragma unroll
        for (int a = 0; a < 2; ++a)
          #pragma unroll
          for (int ns = 0; ns < 4; ++ns)
            acc2[ns] = MFMA16(hb[a], W2F[a][ns], acc2[ns]);   // A-form: C batch-major
        #pragma unroll
        for (int ns = 0; ns < 4; ++ns)
            *(f32x4*)&pbuf[(w * 256 + ns * 64 + lane) * 4] = acc2[ns];

        // ---- u-block in P1 tail: uacc(t+1) = b1 + u(t+1)@W1u ;
        //      prefetch u(t+2) ----
        #pragma unroll
        for (int nf = 0; nf < 4; ++nf) uacc[nf] = b1v[nf];
        {
            f16x2 a01 = pkrtz(ua0[0], ua0[1]), a23 = pkrtz(ua0[2], ua0[3]);
            f16x2 c01 = pkrtz(ua1[0], ua1[1]), c23 = pkrtz(ua1[2], ua1[3]);
            f16x2 la  = pkrtz(ua0[0] - (float)a01[0], ua0[1] - (float)a01[1]);
            f16x2 lb  = pkrtz(ua0[2] - (float)a23[0], ua0[3] - (float)a23[1]);
            f16x2 lc  = pkrtz(ua1[0] - (float)c01[0], ua1[1] - (float)c01[1]);
            f16x2 ld  = pkrtz(ua1[2] - (float)c23[0], ua1[3] - (float)c23[1]);
            f16x8 uh, ul;
            uh[0]=a01[0]; uh[1]=a01[1]; uh[2]=a23[0]; uh[3]=a23[1];
            uh[4]=c01[0]; uh[5]=c01[1]; uh[6]=c23[0]; uh[7]=c23[1];
            ul[0]=la[0];  ul[1]=la[1];  ul[2]=lb[0];  ul[3]=lb[1];
            ul[4]=lc[0];  ul[5]=lc[1];  ul[6]=ld[0];  ul[7]=ld[1];
            #pragma unroll
            for (int nf = 0; nf < 4; ++nf) uacc[nf] = MFMA16(W1Fu[0][nf], uh, uacc[nf]);
            #pragma unroll
            for (int nf = 0; nf < 4; ++nf) uacc[nf] = MFMA16(W1Fu[1][nf], ul, uacc[nf]);
        }
        {
            int tp = (t + 2 < L) ? (t + 2) : (L - 1);
            ua0 = *(const f32x4*)(uptr + (size_t)tp * U);
            ua1 = *(const f32x4*)(uptr + (size_t)tp * U + 4);
        }
        __syncthreads();

        // ---- P2: linear partial reads, tree reduce, state update,
        //          out store, z-write ----
        f32x2 p[8];
        #pragma unroll
        for (int ww = 0; ww < 8; ++ww)
            p[ww] = *(const f32x2*)&pbuf[ww * 1024 + w * 128 + lane * 2];

        f32x2 s01 = (f32x2){0.f, 0.f}, s23 = s01, s45 = s01, s67 = s01;
        #pragma unroll
        for (int j = 0; j < 2; ++j) {
            s01[j] = p[0][j] + p[1][j];
            s23[j] = p[2][j] + p[3][j];
            s45[j] = p[4][j] + p[5][j];
            s67[j] = p[6][j] + p[7][j];
        }
        float d0 = ((s01[0] + s23[0]) + (s45[0] + s67[0])) + b2v;
        float d1 = ((s01[1] + s23[1]) + (s45[1] + s67[1])) + b2v;
        float sn0 = __builtin_fmaf(0.1f, d0, stateF[0]);
        float sn1 = __builtin_fmaf(0.1f, d1, stateF[1]);
        stateF[0] = sn0; stateF[1] = sn1;
        f16x2 sh = pkrtz(sn0, sn1);
        f16x2 sl = pkrtz(sn0 - (float)sh[0], sn1 - (float)sh[1]);
        zbuf[zci]            = sh[0];
        zbuf[zci + 8]        = sh[1];
        zbuf[zci + 1024]     = sl[0];
        zbuf[zci + 1024 + 8] = sl[1];
        out[((size_t)(b0 + bP) * L + t) * S + sP]     = sn0;
        out[((size_t)(b0 + bP + 1) * L + t) * S + sP] = sn1;
        __syncthreads();
    }
}

extern "C" void kernel_launch(void* const* d_in, const int* in_sizes, int n_in,
                              void* d_out, int out_size, void* d_ws, size_t ws_size,
                              hipStream_t stream) {
    const float* init = (const float*)d_in[0];
    const float* uin  = (const float*)d_in[1];
    const float* W1   = (const float*)d_in[2];
    const float* b1   = (const float*)d_in[3];
    const float* W2   = (const float*)d_in[4];
    const float* b2   = (const float*)d_in[5];
    euler_kernel<<<dim3(64), dim3(512), 0, stream>>>(init, uin, W1, b1, W2, b2,
                                                     (float*)d_out);
}